// Round 1
// baseline (117.067 us; speedup 1.0000x reference)
//
#include <hip/hip_runtime.h>

// RelativePositionEncoder: out[b,i,j,:] = W_pos[d_res] + W_tok[d_tok]
//                                        + W_chain[d_chain] + same_entity * w_ent
// B=1, N=1024, TOKEN_Z=128, D_IN=139 (66 pos + 66 tok + 1 ent + 6 chain).
// Write-BW-bound: 537 MB output; W table (71 KB) is cache-resident.

#define N_TOK   1024
#define R_MAX   32
#define S_MAX   2
#define ROW_POS   0
#define ROW_TOK   66
#define ROW_ENT   132
#define ROW_CHAIN 133

__global__ __launch_bounds__(256) void relpos_kernel(
    const int*   __restrict__ asym_id,
    const int*   __restrict__ residue_index,
    const int*   __restrict__ entity_id,
    const int*   __restrict__ token_index,
    const int*   __restrict__ sym_id,
    const float* __restrict__ W,      // 139 x 128 row-major f32
    float*       __restrict__ out)    // 1024 x 1024 x 128 f32
{
    const long long tid = (long long)blockIdx.x * blockDim.x + threadIdx.x;
    const int pair = (int)(tid >> 5);       // 32 float4-slots per pair
    const int slot = (int)(tid & 31);       // which float4 of the 128 channels
    if (pair >= N_TOK * N_TOK) return;

    const int i = pair >> 10;               // N_TOK = 1024
    const int j = pair & (N_TOK - 1);

    const int ai = asym_id[i],       aj = asym_id[j];
    const int ri = residue_index[i], rj = residue_index[j];
    const int ti = token_index[i],   tj = token_index[j];
    const int si = sym_id[i],        sj = sym_id[j];
    const int ei = entity_id[i],     ej = entity_id[j];

    const bool same_chain = (ai == aj);
    const bool same_res   = (ri == rj);

    int d_res = min(max(ri - rj + R_MAX, 0), 2 * R_MAX);
    if (!same_chain) d_res = 2 * R_MAX + 1;

    int d_tok = min(max(ti - tj + R_MAX, 0), 2 * R_MAX);
    if (!(same_chain && same_res)) d_tok = 2 * R_MAX + 1;

    int d_chain = same_chain ? (2 * S_MAX + 1)
                             : min(max(si - sj + S_MAX, 0), 2 * S_MAX);

    const float4* __restrict__ W4 = (const float4*)W;   // 139 rows x 32 float4
    const float4 a = W4[(ROW_POS   + d_res)   * 32 + slot];
    const float4 b = W4[(ROW_TOK   + d_tok)   * 32 + slot];
    const float4 c = W4[(ROW_CHAIN + d_chain) * 32 + slot];

    float4 r;
    r.x = a.x + b.x + c.x;
    r.y = a.y + b.y + c.y;
    r.z = a.z + b.z + c.z;
    r.w = a.w + b.w + c.w;

    if (ei == ej) {
        const float4 e = W4[ROW_ENT * 32 + slot];
        r.x += e.x; r.y += e.y; r.z += e.z; r.w += e.w;
    }

    ((float4*)out)[(long long)pair * 32 + slot] = r;
}

extern "C" void kernel_launch(void* const* d_in, const int* in_sizes, int n_in,
                              void* d_out, int out_size, void* d_ws, size_t ws_size,
                              hipStream_t stream) {
    const int*   asym_id       = (const int*)d_in[0];
    const int*   residue_index = (const int*)d_in[1];
    const int*   entity_id     = (const int*)d_in[2];
    const int*   token_index   = (const int*)d_in[3];
    const int*   sym_id        = (const int*)d_in[4];
    const float* W             = (const float*)d_in[5];
    float*       out           = (float*)d_out;

    const long long total_threads = (long long)N_TOK * N_TOK * 32;  // one float4 each
    const int block = 256;
    const int grid  = (int)((total_threads + block - 1) / block);   // 131072

    relpos_kernel<<<grid, block, 0, stream>>>(
        asym_id, residue_index, entity_id, token_index, sym_id, W, out);
}

// Round 2
// 106.418 us; speedup vs baseline: 1.1001x; 1.1001x over previous
//
#include <hip/hip_runtime.h>

// RelativePositionEncoder: out[i,j,:] = W_pos[d_res] + W_tok[d_tok]
//                                      + W_chain[d_chain] + same_entity * w_ent
// B=1, N=1024, TOKEN_Z=128, W is 139x128 f32 (66 pos + 66 tok + 1 ent + 6 chain).
// Write-BW-bound: 537 MB output. Strategy: block = 64 pairs (one i), packed
// bin-indices precomputed once per pair into LDS, then 8 coalesced float4
// stores per thread with fixed channel slot.

#define N_TOK   1024
#define R_MAX   32
#define S_MAX   2
#define ROW_POS   0
#define ROW_TOK   66
#define ROW_ENT   132
#define ROW_CHAIN 133

__global__ __launch_bounds__(256) void relpos_kernel(
    const int*   __restrict__ asym_id,
    const int*   __restrict__ residue_index,
    const int*   __restrict__ entity_id,
    const int*   __restrict__ token_index,
    const int*   __restrict__ sym_id,
    const float* __restrict__ W,      // 139 x 128 row-major f32
    float*       __restrict__ out)    // 1024 x 1024 x 128 f32
{
    __shared__ int s_idx[64];

    const int tid = threadIdx.x;
    const int i   = blockIdx.x >> 4;          // 16 blocks per i-row
    const int j0  = (blockIdx.x & 15) << 6;   // 64 j's per block

    if (tid < 64) {
        const int j  = j0 + tid;
        const int ai = asym_id[i],       aj = asym_id[j];
        const int ri = residue_index[i], rj = residue_index[j];
        const int ti = token_index[i],   tj = token_index[j];
        const int si = sym_id[i],        sj = sym_id[j];
        const int ei = entity_id[i],     ej = entity_id[j];

        const bool same_chain = (ai == aj);
        const bool same_res   = (ri == rj);

        int d_res = min(max(ri - rj + R_MAX, 0), 2 * R_MAX);
        if (!same_chain) d_res = 2 * R_MAX + 1;

        int d_tok = min(max(ti - tj + R_MAX, 0), 2 * R_MAX);
        if (!(same_chain && same_res)) d_tok = 2 * R_MAX + 1;

        const int d_chain = same_chain ? (2 * S_MAX + 1)
                                       : min(max(si - sj + S_MAX, 0), 2 * S_MAX);
        const int ent = (ei == ej) ? 1 : 0;

        s_idx[tid] = d_res | (d_tok << 7) | (d_chain << 14) | (ent << 17);
    }
    __syncthreads();

    const int slot    = tid & 31;   // fixed float4 channel slot per thread
    const int plocal0 = tid >> 5;   // 0..7

    const float4* __restrict__ W4 = (const float4*)W;  // 139 rows x 32 float4
    const float4 e = W4[ROW_ENT * 32 + slot];          // loop-invariant

    float4* __restrict__ outp = (float4*)out + ((long long)blockIdx.x << 11);

    #pragma unroll
    for (int iter = 0; iter < 8; ++iter) {
        const int pl      = plocal0 + iter * 8;      // pair-local index 0..63
        const int packed  = s_idx[pl];
        const int d_res   =  packed        & 127;
        const int d_tok   = (packed >> 7)  & 127;
        const int d_chain = (packed >> 14) & 7;
        const float m     = (packed & (1 << 17)) ? 1.0f : 0.0f;

        const float4 a = W4[(ROW_POS   + d_res)   * 32 + slot];
        const float4 b = W4[(ROW_TOK   + d_tok)   * 32 + slot];
        const float4 c = W4[(ROW_CHAIN + d_chain) * 32 + slot];

        float4 r;
        r.x = a.x + b.x + c.x + m * e.x;
        r.y = a.y + b.y + c.y + m * e.y;
        r.z = a.z + b.z + c.z + m * e.z;
        r.w = a.w + b.w + c.w + m * e.w;

        outp[pl * 32 + slot] = r;
    }
}

extern "C" void kernel_launch(void* const* d_in, const int* in_sizes, int n_in,
                              void* d_out, int out_size, void* d_ws, size_t ws_size,
                              hipStream_t stream) {
    const int*   asym_id       = (const int*)d_in[0];
    const int*   residue_index = (const int*)d_in[1];
    const int*   entity_id     = (const int*)d_in[2];
    const int*   token_index   = (const int*)d_in[3];
    const int*   sym_id        = (const int*)d_in[4];
    const float* W             = (const float*)d_in[5];
    float*       out           = (float*)d_out;

    const int grid  = (N_TOK * N_TOK) / 64;   // 16384 blocks, 64 pairs each
    const int block = 256;

    relpos_kernel<<<grid, block, 0, stream>>>(
        asym_id, residue_index, entity_id, token_index, sym_id, W, out);
}